// Round 9
// baseline (257.363 us; speedup 1.0000x reference)
//
#include <hip/hip_runtime.h>
#include <hip/hip_bf16.h>

#define N_   16
#define CI_  256
#define CO_  256
#define D_   4096
#define DO_  8192
#define KTOT 768            // 3 taps (j outer) x 256 ci
#define XTROWS 4098         // 4096 t + 1 zero pad row each side
#define WT_ELEMS (512 * KTOT)
#define XT_ELEMS ((size_t)N_ * XTROWS * 256)

typedef short frag8 __attribute__((ext_vector_type(8)));   // 8 bf16 (4 VGPR)
typedef float facc4 __attribute__((ext_vector_type(4)));   // 4 f32 acc

static __device__ __forceinline__ unsigned short f2bf(float f) {
    union { __hip_bfloat16 h; unsigned short u; } cv;
    cv.h = __float2bfloat16(f);
    return cv.u;
}

static __device__ __forceinline__ unsigned int pack2(float lo, float hi) {
    return (unsigned int)f2bf(lo) | ((unsigned int)f2bf(hi) << 16);
}

static __device__ __forceinline__ void async16(unsigned short* lds, const unsigned short* g) {
    __builtin_amdgcn_global_load_lds(
        (const __attribute__((address_space(1))) unsigned int*)g,
        (__attribute__((address_space(3))) unsigned int*)lds, 16, 0, 0);
}

// opaque LDS read: no "memory" clobber -> compiler has no alias edge to the
// in-flight global_load_lds writes, so it cannot insert vmcnt(0) drains.
#define DSR_(dst, addr, litstr) \
    asm volatile("ds_read_b128 %0, %1 offset:" litstr : "=&v"(dst) : "v"(addr))

// ---------------- merged prep: weights + x transpose in ONE launch -------
__global__ __launch_bounds__(256) void prep_all(const float* __restrict__ x,
                                                const float* __restrict__ w,
                                                unsigned short* __restrict__ Wt,
                                                unsigned short* __restrict__ xt) {
    const int tid = threadIdx.x;

    if (blockIdx.x == 128) {
        // ---- prep_wt body: co range [y*16, y*16+16) ----
        const int ci = tid;
        #pragma unroll 2
        for (int i = 0; i < 16; ++i) {
            const int co = blockIdx.y * 16 + i;
            const float* wp = w + ((size_t)co * CI_ + ci) * 3;
            const float w0 = wp[0], w1 = wp[1], w2 = wp[2];
            const float e0 = 0.25f * w1 + 0.75f * w0;
            const float e1 = 0.75f * w2 + 0.75f * w1 + 0.25f * w0;
            const float e2 = 0.25f * w2;
            const float o0 = 0.25f * w0;
            const float o1 = 0.25f * w2 + 0.75f * w1 + 0.75f * w0;
            const float o2 = 0.75f * w2 + 0.25f * w1;
            unsigned short* pe = Wt + (size_t)(co * 2 + 0) * KTOT;
            unsigned short* po = Wt + (size_t)(co * 2 + 1) * KTOT;
            pe[0 * 256 + ci] = f2bf(e0); pe[1 * 256 + ci] = f2bf(e1); pe[2 * 256 + ci] = f2bf(e2);
            po[0 * 256 + ci] = f2bf(o0); po[1 * 256 + ci] = f2bf(o1); po[2 * 256 + ci] = f2bf(o2);
        }
        return;
    }

    // ---- prep_xt2 body (verified r0-r8) ----
    __shared__ unsigned int Lp[32][133];   // [t][ci_pair], pitch 133
    const int t0  = blockIdx.x * 32;
    const int n   = blockIdx.y;
    const float* xn = x + (size_t)n * CI_ * D_;
    unsigned short* slab = xt + (size_t)n * XTROWS * 256;

    if (t0 == 0 && tid < 128)       ((unsigned int*)slab)[tid] = 0u;
    if (t0 == D_ - 32 && tid < 128) ((unsigned int*)(slab + (size_t)(XTROWS - 1) * 256))[tid] = 0u;

    const int cp_l  = tid >> 3;
    const int t_off = (tid & 7) * 4;

    #pragma unroll
    for (int p = 0; p < 4; ++p) {
        const int ci0 = p * 64 + cp_l * 2;
        float4 a = *(const float4*)(xn + (size_t)ci0 * D_ + t0 + t_off);
        float4 b = *(const float4*)(xn + (size_t)(ci0 + 1) * D_ + t0 + t_off);
        const int cp = p * 32 + cp_l;
        Lp[t_off + 0][cp] = pack2(a.x, b.x);
        Lp[t_off + 1][cp] = pack2(a.y, b.y);
        Lp[t_off + 2][cp] = pack2(a.z, b.z);
        Lp[t_off + 3][cp] = pack2(a.w, b.w);
    }
    __syncthreads();

    #pragma unroll
    for (int it = 0; it < 4; ++it) {
        const int row = it * 8 + (tid >> 5);
        const int c4  = (tid & 31) * 4;
        uint4 v;
        v.x = Lp[row][c4 + 0];
        v.y = Lp[row][c4 + 1];
        v.z = Lp[row][c4 + 2];
        v.w = Lp[row][c4 + 3];
        *(uint4*)(slab + (size_t)(1 + t0 + row) * 256 + c4 * 2) = v;
    }
}

// ---------------- main: 256m x 256t, B DIRECT FROM GLOBAL ----------------
// Round-9 datapath change: B never touches LDS.  xt's [t][k] layout IS the
// MFMA B-fragment layout: lane (quad,l16) of wave (wt) loads its 16B frag at
// xt + (bt0+wt+ti*16+l16)*256 + u*64 + kh*32 + quad*8 (all u/kh/ti offsets
// fold into the 13-bit imm).  B frags prefetched one K-tile ahead into regs
// (compiler-tracked vmcnt; a full tile of MFMA hides L3 latency).
// Removes: B DMA (32KB/kt), B ds_reads (64 instr/CU/kt) -> LDS port load
// drops from ~2816 to ~1790 cyc/kt, below MFMA's 2483.
// A path byte-identical to r4/r8 (slot-XOR, 0 conflicts, 2-deep dbuf);
// 2 barriers/K-tile + counted lgkm groups (r8-verified).
// vmcnt FIFO audit (per thread, steady): [b(u)8 | A(u+1)4 | b(u+1)8 | A(u+2)4];
// compiler's Q0 wait drains b(u) exactly (leaves 12+); gate vmcnt(12) drains
// A(u+1), keeps b(u+1)+A(u+2).  u=10 gate: vmcnt(8).  u=11: vmcnt(0).
__global__ __launch_bounds__(512, 2) void gemm_bdir(
    const unsigned short* __restrict__ Wt, const unsigned short* __restrict__ xt,
    const float* __restrict__ bias, float* __restrict__ out)
{
    __shared__ __align__(16) unsigned short SL[32768];   // 64 KiB: A dbuf only

    const int tid  = threadIdx.x;
    const int lane = tid & 63;
    const int wid  = tid >> 6;          // 0..7
    const int quad = lane >> 4;
    const int l16  = lane & 15;

    const int bt0 = blockIdx.x * 256;   // t tile
    const int bm0 = blockIdx.y * 256;   // m tile (m = co*2+phase)
    const int n   = blockIdx.z;

    // ---- A staging (identical to r4/r8) ----
    const int srow = wid * 16 + (lane >> 2);            // 0..127 row in half
    const int cg   = (lane & 3) ^ ((lane >> 3) & 3);    // slot-XOR
    const unsigned short* sA = Wt + (size_t)(bm0 + srow) * KTOT + cg * 8;

    #define STAGE_A(u, mh) do {                                                     \
        async16(SL + (((u)&1)*16384 + (mh)*8192 + 0*4096 + wid*512),                \
                sA + (size_t)(mh)*128*KTOT + (u)*64 + 0);                           \
        async16(SL + (((u)&1)*16384 + (mh)*8192 + 1*4096 + wid*512),                \
                sA + (size_t)(mh)*128*KTOT + (u)*64 + 32); } while (0)

    // ---- A fragment read base (bytes) ----
    const int swz = quad ^ ((l16 >> 1) & 3);
    const int mh  = wid & 1;              // wave m-half
    const int wm  = mh * 128;
    const int wt  = ((wid >> 1) & 3) * 64;
    const unsigned base = (unsigned)(size_t)&SL[0];
    const unsigned aB = base + (unsigned)(mh * 16384 + l16 * 64 + swz * 16);

    // ---- B direct-gather bases (ushort units); per-lane, u-invariant ----
    const unsigned short* xtn = xt + (size_t)n * XTROWS * 256;
    const unsigned short* bp[4];
    #pragma unroll
    for (int ti = 0; ti < 4; ++ti)
        bp[ti] = xtn + (size_t)(bt0 + wt + ti * 16 + l16) * 256 + quad * 8;

    facc4 acc[8][4] = {};
    frag8 bbuf[2][4][2];

    // ---- prologue: A(0), A(1) DMA; b(0) gathers ----
    STAGE_A(0, 0); STAGE_A(0, 1);
    STAGE_A(1, 0); STAGE_A(1, 1);
    #pragma unroll
    for (int ti = 0; ti < 4; ++ti) {
        bbuf[0][ti][0] = *(const frag8*)(bp[ti] + 0);
        bbuf[0][ti][1] = *(const frag8*)(bp[ti] + 32);
    }
    asm volatile("s_waitcnt vmcnt(12)" ::: "memory");  // drain A(0); keep A(1)+b(0)
    __builtin_amdgcn_s_barrier();

    #define MM(m, t)                                                                 \
        acc[m][t] = __builtin_amdgcn_mfma_f32_16x16x32_bf16(a[m][0], bbuf[u & 1][t][0], acc[m][t], 0, 0, 0); \
        acc[m][t] = __builtin_amdgcn_mfma_f32_16x16x32_bf16(a[m][1], bbuf[u & 1][t][1], acc[m][t], 0, 0, 0);
    #define MMROW(m) MM(m,0) MM(m,1) MM(m,2) MM(m,3)

    #define LGKM(lit) \
        asm volatile("s_waitcnt lgkmcnt(" lit ")" ::: "memory"); \
        __builtin_amdgcn_sched_barrier(0);

    #pragma unroll
    for (int u = 0; u < 12; ++u) {
        const unsigned au = aB + (unsigned)((u & 1) << 15);
        frag8 a[8][2];

        // prefetch next K-tile's B frags (plain loads; compiler tracks vmcnt)
        if (u < 11) {
            #pragma unroll
            for (int ti = 0; ti < 4; ++ti) {
                bbuf[(u + 1) & 1][ti][0] = *(const frag8*)(bp[ti] + (u + 1) * 64);
                bbuf[(u + 1) & 1][ti][1] = *(const frag8*)(bp[ti] + (u + 1) * 64 + 32);
            }
        }

        // A rows 0-3 (8 ds_reads), counted-lgkm groups (r8-verified pattern)
        DSR_(a[0][0], au, "0");    DSR_(a[0][1], au, "8192");
        DSR_(a[1][0], au, "1024"); DSR_(a[1][1], au, "9216");
        DSR_(a[2][0], au, "2048"); DSR_(a[2][1], au, "10240");
        DSR_(a[3][0], au, "3072"); DSR_(a[3][1], au, "11264");
        LGKM("4")                            // a0,a1 ready
        __builtin_amdgcn_s_setprio(1);
        MMROW(0) MMROW(1)
        __builtin_amdgcn_s_setprio(0);

        DSR_(a[4][0], au, "4096"); DSR_(a[4][1], au, "12288");
        DSR_(a[5][0], au, "5120"); DSR_(a[5][1], au, "13312");
        LGKM("4")                            // a2,a3 ready
        __builtin_amdgcn_s_setprio(1);
        MMROW(2) MMROW(3)
        __builtin_amdgcn_s_setprio(0);

        DSR_(a[6][0], au, "6144"); DSR_(a[6][1], au, "14336");
        DSR_(a[7][0], au, "7168"); DSR_(a[7][1], au, "15360");
        LGKM("4")                            // a4,a5 ready
        __builtin_amdgcn_s_setprio(1);
        MMROW(4) MMROW(5)
        __builtin_amdgcn_s_setprio(0);

        LGKM("0")                            // all A reads of this par done
        __builtin_amdgcn_s_barrier();        // M: re-staging par is safe

        if (u < 10) { STAGE_A(u + 2, 0); STAGE_A(u + 2, 1); }

        __builtin_amdgcn_s_setprio(1);
        MMROW(6) MMROW(7)                    // hide A-DMA issue
        __builtin_amdgcn_s_setprio(0);

        if (u < 10)       { asm volatile("s_waitcnt vmcnt(12)" ::: "memory"); }
        else if (u == 10) { asm volatile("s_waitcnt vmcnt(8)"  ::: "memory"); }
        else              { asm volatile("s_waitcnt vmcnt(0)"  ::: "memory"); }
        __builtin_amdgcn_s_barrier();        // E: next tile's A resident
    }
    #undef MM
    #undef MMROW
    #undef LGKM
    #undef STAGE_A

    // epilogue: D row = quad*4+reg (= m), col = l16 (= t); regs span 2 co x 2 phase
    #pragma unroll
    for (int m8 = 0; m8 < 8; ++m8) {
        int m0  = bm0 + wm + m8 * 16 + quad * 4;
        int co0 = m0 >> 1;
        float b0 = bias[co0];
        float b1 = bias[co0 + 1];
        #pragma unroll
        for (int t4 = 0; t4 < 4; ++t4) {
            int t = bt0 + wt + t4 * 16 + l16;
            facc4 v = acc[m8][t4];
            float* p0 = out + ((size_t)(n * CO_ + co0)) * DO_ + 2 * t;
            float* p1 = p0 + DO_;
            *(float2*)p0 = make_float2(v.x + b0, v.y + b0);
            *(float2*)p1 = make_float2(v.z + b1, v.w + b1);
        }
    }
}

// ---------------- fallback (round-1 verified kernel) ---------------------
__global__ __launch_bounds__(256) void upconv_fir_f32(
    const float* __restrict__ x, const float* __restrict__ w,
    const float* __restrict__ bias, float* __restrict__ out)
{
    __shared__ float ws[CI_][4];
    const int tid = threadIdx.x;
    const int co  = blockIdx.y;
    const int n   = blockIdx.z;
    {
        const float* wc = w + (size_t)co * CI_ * 3;
        ws[tid][0] = wc[tid * 3 + 0];
        ws[tid][1] = wc[tid * 3 + 1];
        ws[tid][2] = wc[tid * 3 + 2];
        ws[tid][3] = 0.f;
    }
    __syncthreads();
    const int t0 = (blockIdx.x * 256 + tid) * 8;
    const float* xn = x + (size_t)n * CI_ * D_;
    float s[10], g[9];
    #pragma unroll
    for (int k = 0; k < 10; ++k) s[k] = 0.f;
    #pragma unroll
    for (int k = 0; k < 9; ++k) g[k] = 0.f;
    #pragma unroll 2
    for (int ci = 0; ci < CI_; ++ci) {
        const float* xr = xn + ci * D_;
        float4 va = *(const float4*)(xr + t0);
        float4 vb = *(const float4*)(xr + t0 + 4);
        float  xm = (t0 > 0)      ? xr[t0 - 1] : 0.f;
        float  xp = (t0 + 8 < D_) ? xr[t0 + 8] : 0.f;
        float4 wv = *(const float4*)(&ws[ci][0]);
        const float w0 = wv.x, w1 = wv.y, w2 = wv.z;
        float xa[10];
        xa[0] = xm; xa[1] = va.x; xa[2] = va.y; xa[3] = va.z; xa[4] = va.w;
        xa[5] = vb.x; xa[6] = vb.y; xa[7] = vb.z; xa[8] = vb.w; xa[9] = xp;
        #pragma unroll
        for (int k = 0; k < 10; ++k) s[k] += w1 * xa[k];
        #pragma unroll
        for (int k = 0; k < 9; ++k)  g[k] += w0 * xa[k] + w2 * xa[k + 1];
    }
    const float b = bias[co];
    float o16[16];
    #pragma unroll
    for (int tt = 0; tt < 8; ++tt) {
        o16[2 * tt]     = 0.25f * (s[tt] + g[tt + 1]) + 0.75f * (g[tt] + s[tt + 1]) + b;
        o16[2 * tt + 1] = 0.25f * (g[tt] + s[tt + 2]) + 0.75f * (s[tt + 1] + g[tt + 1]) + b;
    }
    float* ob = out + ((size_t)n * CO_ + co) * DO_ + 2 * t0;
    *(float4*)(ob + 0)  = make_float4(o16[0],  o16[1],  o16[2],  o16[3]);
    *(float4*)(ob + 4)  = make_float4(o16[4],  o16[5],  o16[6],  o16[7]);
    *(float4*)(ob + 8)  = make_float4(o16[8],  o16[9],  o16[10], o16[11]);
    *(float4*)(ob + 12) = make_float4(o16[12], o16[13], o16[14], o16[15]);
}

extern "C" void kernel_launch(void* const* d_in, const int* in_sizes, int n_in,
                              void* d_out, int out_size, void* d_ws, size_t ws_size,
                              hipStream_t stream) {
    const float* x  = (const float*)d_in[0];
    const float* w  = (const float*)d_in[1];
    const float* b  = (const float*)d_in[2];
    float* out      = (float*)d_out;

    const size_t need = (size_t)WT_ELEMS * 2 + XT_ELEMS * 2;
    if (ws_size >= need) {
        unsigned short* Wt = (unsigned short*)d_ws;
        unsigned short* xt = Wt + WT_ELEMS;
        prep_all<<<dim3(D_ / 32 + 1, N_), 256, 0, stream>>>(x, w, Wt, xt);
        gemm_bdir<<<dim3(D_ / 256, 2, N_), 512, 0, stream>>>(Wt, xt, b, out);
    } else {
        upconv_fir_f32<<<dim3(2, CO_, N_), 256, 0, stream>>>(x, w, b, out);
    }
}

// Round 10
// 255.130 us; speedup vs baseline: 1.0088x; 1.0088x over previous
//
#include <hip/hip_runtime.h>
#include <hip/hip_bf16.h>

#define N_   16
#define CI_  256
#define CO_  256
#define D_   4096
#define DO_  8192
#define KTOT 768            // 3 taps (j outer) x 256 ci
#define XTROWS 4098         // 4096 t + 1 zero pad row each side
#define WT_ELEMS (512 * KTOT)
#define XT_ELEMS ((size_t)N_ * XTROWS * 256)

typedef short frag8 __attribute__((ext_vector_type(8)));   // 8 bf16 (4 VGPR)
typedef float facc4 __attribute__((ext_vector_type(4)));   // 4 f32 acc

static __device__ __forceinline__ unsigned short f2bf(float f) {
    union { __hip_bfloat16 h; unsigned short u; } cv;
    cv.h = __float2bfloat16(f);
    return cv.u;
}

static __device__ __forceinline__ unsigned int pack2(float lo, float hi) {
    return (unsigned int)f2bf(lo) | ((unsigned int)f2bf(hi) << 16);
}

static __device__ __forceinline__ void async16(unsigned short* lds, const unsigned short* g) {
    __builtin_amdgcn_global_load_lds(
        (const __attribute__((address_space(1))) unsigned int*)g,
        (__attribute__((address_space(3))) unsigned int*)lds, 16, 0, 0);
}

// opaque LDS read: no "memory" clobber -> compiler has no alias edge to the
// in-flight global_load_lds writes, so it cannot insert vmcnt(0) drains.
#define DSR_(dst, addr, litstr) \
    asm volatile("ds_read_b128 %0, %1 offset:" litstr : "=&v"(dst) : "v"(addr))

// ---------------- merged prep: weights + x transpose in ONE launch -------
__global__ __launch_bounds__(256) void prep_all(const float* __restrict__ x,
                                                const float* __restrict__ w,
                                                unsigned short* __restrict__ Wt,
                                                unsigned short* __restrict__ xt) {
    const int tid = threadIdx.x;

    if (blockIdx.x == 128) {
        // ---- prep_wt body: co range [y*16, y*16+16) ----
        const int ci = tid;
        #pragma unroll 2
        for (int i = 0; i < 16; ++i) {
            const int co = blockIdx.y * 16 + i;
            const float* wp = w + ((size_t)co * CI_ + ci) * 3;
            const float w0 = wp[0], w1 = wp[1], w2 = wp[2];
            const float e0 = 0.25f * w1 + 0.75f * w0;
            const float e1 = 0.75f * w2 + 0.75f * w1 + 0.25f * w0;
            const float e2 = 0.25f * w2;
            const float o0 = 0.25f * w0;
            const float o1 = 0.25f * w2 + 0.75f * w1 + 0.75f * w0;
            const float o2 = 0.75f * w2 + 0.25f * w1;
            unsigned short* pe = Wt + (size_t)(co * 2 + 0) * KTOT;
            unsigned short* po = Wt + (size_t)(co * 2 + 1) * KTOT;
            pe[0 * 256 + ci] = f2bf(e0); pe[1 * 256 + ci] = f2bf(e1); pe[2 * 256 + ci] = f2bf(e2);
            po[0 * 256 + ci] = f2bf(o0); po[1 * 256 + ci] = f2bf(o1); po[2 * 256 + ci] = f2bf(o2);
        }
        return;
    }

    // ---- prep_xt2 body (verified r0-r9) ----
    __shared__ unsigned int Lp[32][133];   // [t][ci_pair], pitch 133
    const int t0  = blockIdx.x * 32;
    const int n   = blockIdx.y;
    const float* xn = x + (size_t)n * CI_ * D_;
    unsigned short* slab = xt + (size_t)n * XTROWS * 256;

    if (t0 == 0 && tid < 128)       ((unsigned int*)slab)[tid] = 0u;
    if (t0 == D_ - 32 && tid < 128) ((unsigned int*)(slab + (size_t)(XTROWS - 1) * 256))[tid] = 0u;

    const int cp_l  = tid >> 3;
    const int t_off = (tid & 7) * 4;

    #pragma unroll
    for (int p = 0; p < 4; ++p) {
        const int ci0 = p * 64 + cp_l * 2;
        float4 a = *(const float4*)(xn + (size_t)ci0 * D_ + t0 + t_off);
        float4 b = *(const float4*)(xn + (size_t)(ci0 + 1) * D_ + t0 + t_off);
        const int cp = p * 32 + cp_l;
        Lp[t_off + 0][cp] = pack2(a.x, b.x);
        Lp[t_off + 1][cp] = pack2(a.y, b.y);
        Lp[t_off + 2][cp] = pack2(a.z, b.z);
        Lp[t_off + 3][cp] = pack2(a.w, b.w);
    }
    __syncthreads();

    #pragma unroll
    for (int it = 0; it < 4; ++it) {
        const int row = it * 8 + (tid >> 5);
        const int c4  = (tid & 31) * 4;
        uint4 v;
        v.x = Lp[row][c4 + 0];
        v.y = Lp[row][c4 + 1];
        v.z = Lp[row][c4 + 2];
        v.w = Lp[row][c4 + 3];
        *(uint4*)(slab + (size_t)(1 + t0 + row) * 256 + c4 * 2) = v;
    }
}

// ---------------- main: persistent 2-tile, r8-verified K-loop ------------
// Each block processes TWO adjacent 256t tiles (half = 0,1).  Removes one
// full generation boundary of r8 (endpgm store-drain + relaunch + cold 2-kt
// pipeline ramp); tile-0 epilogue stores are issued without waiting and
// drain under tile-1's prologue DMA + early K-tiles.  Store-safety: all
// tile-0 stores are OLDER than every tile-1 vmem load, so r8's counted
// vmcnt gates remain correct (conservative only).  A-panel (same bm0) is
// L2-hot for the second tile.  K-loop body byte-identical to r8 (best,
// 233.9 us): 2 barriers/K-tile + counted lgkm groups + vmcnt(4) gate,
// slot-XOR LDS layout (0 bank conflicts r0-r9).
__global__ __launch_bounds__(512, 2) void gemm_upfir8p(
    const unsigned short* __restrict__ Wt, const unsigned short* __restrict__ xt,
    const float* __restrict__ bias, float* __restrict__ out)
{
    __shared__ __align__(16) unsigned short SL[65536];   // 128 KiB

    const int tid  = threadIdx.x;
    const int lane = tid & 63;
    const int wid  = tid >> 6;          // 0..7
    const int quad = lane >> 4;
    const int l16  = lane & 15;

    const int bm0 = blockIdx.y * 256;   // m tile (m = co*2+phase)
    const int n   = blockIdx.z;

    // ---- staging addressing (all 8 waves stage every half-tile) ----
    const int srow = wid * 16 + (lane >> 2);            // 0..127 row in half
    const int cg   = (lane & 3) ^ ((lane >> 3) & 3);    // slot-XOR
    const unsigned short* sA = Wt + (size_t)(bm0 + srow) * KTOT + cg * 8;
    const unsigned short* xtn = xt + (size_t)n * XTROWS * 256;

    #define STAGE_A(u, mh) do {                                                     \
        async16(SL + (((u)&1)*16384 + (mh)*8192 + 0*4096 + wid*512),                \
                sA + (size_t)(mh)*128*KTOT + (u)*64 + 0);                           \
        async16(SL + (((u)&1)*16384 + (mh)*8192 + 1*4096 + wid*512),                \
                sA + (size_t)(mh)*128*KTOT + (u)*64 + 32); } while (0)
    #define STAGE_B(u, th) do {                                                     \
        async16(SL + (32768 + ((u)&1)*16384 + (th)*8192 + 0*4096 + wid*512),        \
                sB + (size_t)(th)*128*256 + (u)*64 + 0);                            \
        async16(SL + (32768 + ((u)&1)*16384 + (th)*8192 + 1*4096 + wid*512),        \
                sB + (size_t)(th)*128*256 + (u)*64 + 32); } while (0)

    // ---- fragment read bases (byte addresses) ----
    const int swz = quad ^ ((l16 >> 1) & 3);
    const int mh  = wid & 1;              // wave m-half
    const int wm  = mh * 128;
    const int wt  = ((wid >> 1) & 3) * 64;
    const unsigned base = (unsigned)(size_t)&SL[0];
    const unsigned aB = base + (unsigned)(mh * 16384 + l16 * 64 + swz * 16);
    const unsigned bB = base + 65536u
                      + (unsigned)(((wid >> 2) & 1) * 16384
                                   + (((wid >> 1) & 1) * 64 + l16) * 64 + swz * 16);

    #define MM(m, t)                                                                 \
        acc[m][t] = __builtin_amdgcn_mfma_f32_16x16x32_bf16(a[m][0], b[t][0], acc[m][t], 0, 0, 0); \
        acc[m][t] = __builtin_amdgcn_mfma_f32_16x16x32_bf16(a[m][1], b[t][1], acc[m][t], 0, 0, 0);
    #define MMROW(m) MM(m,0) MM(m,1) MM(m,2) MM(m,3)

    #define LGKM(lit) \
        asm volatile("s_waitcnt lgkmcnt(" lit ")" ::: "memory"); \
        __builtin_amdgcn_sched_barrier(0);

    #pragma unroll 1
    for (int half = 0; half < 2; ++half) {
        const int bt0 = (blockIdx.x * 2 + half) * 256;   // t tile
        const unsigned short* sB = xtn + (size_t)(bt0 + srow) * 256 + cg * 8;

        facc4 acc[8][4] = {};

        // ---- prologue: stage half-tiles A0,B0,A1 (12 loads/thread) ----
        // (half=1: tile-0 epilogue stores are older; vmcnt(4) additionally
        //  drains them -- conservative, correct)
        STAGE_A(0, 0); STAGE_A(0, 1); STAGE_B(0, 0); STAGE_B(0, 1);
        STAGE_A(1, 0); STAGE_A(1, 1);
        asm volatile("s_waitcnt vmcnt(4)" ::: "memory");   // K-tile 0 landed, A1 flying
        __builtin_amdgcn_s_barrier();

        #pragma unroll 2
        for (int u = 0; u < 12; ++u) {
            const unsigned au = aB + (unsigned)((u & 1) << 15);
            const unsigned bu = bB + (unsigned)((u & 1) << 15);
            frag8 a[8][2], b[4][2];

            // issue all B frags + A rows 0-3 (16 ds_reads)
            DSR_(b[0][0], bu, "0");    DSR_(b[0][1], bu, "8192");
            DSR_(b[1][0], bu, "1024"); DSR_(b[1][1], bu, "9216");
            DSR_(b[2][0], bu, "2048"); DSR_(b[2][1], bu, "10240");
            DSR_(b[3][0], bu, "3072"); DSR_(b[3][1], bu, "11264");
            DSR_(a[0][0], au, "0");    DSR_(a[0][1], au, "8192");
            DSR_(a[1][0], au, "1024"); DSR_(a[1][1], au, "9216");
            DSR_(a[2][0], au, "2048"); DSR_(a[2][1], au, "10240");
            DSR_(a[3][0], au, "3072"); DSR_(a[3][1], au, "11264");

            LGKM("6")                           // b0-3 + a0 done
            __builtin_amdgcn_s_setprio(1);
            MMROW(0)
            __builtin_amdgcn_s_setprio(0);
            LGKM("4")                           // a1 done
            __builtin_amdgcn_s_setprio(1);
            MMROW(1)
            __builtin_amdgcn_s_setprio(0);

            // issue A rows 4-7 (8 ds_reads) under the remaining MFMA groups
            DSR_(a[4][0], au, "4096"); DSR_(a[4][1], au, "12288");
            DSR_(a[5][0], au, "5120"); DSR_(a[5][1], au, "13312");
            DSR_(a[6][0], au, "6144"); DSR_(a[6][1], au, "14336");
            DSR_(a[7][0], au, "7168"); DSR_(a[7][1], au, "15360");

            LGKM("10")                          // a2 done
            __builtin_amdgcn_s_setprio(1);
            MMROW(2)
            __builtin_amdgcn_s_setprio(0);
            LGKM("8")                           // a3 done
            __builtin_amdgcn_s_setprio(1);
            MMROW(3)
            __builtin_amdgcn_s_setprio(0);

            LGKM("0")                           // all 24 reads of this tile done
            __builtin_amdgcn_s_barrier();       // M: re-staging is now safe

            if (u < 11) { STAGE_B(u + 1, 0); STAGE_B(u + 1, 1); }
            if (u < 10) { STAGE_A(u + 2, 0); STAGE_A(u + 2, 1); }

            __builtin_amdgcn_s_setprio(1);
            MMROW(4) MMROW(5) MMROW(6) MMROW(7) // 32 MFMA hide the staging DMA
            __builtin_amdgcn_s_setprio(0);

            if (u < 10) { asm volatile("s_waitcnt vmcnt(4)" ::: "memory"); }
            else        { asm volatile("s_waitcnt vmcnt(0)" ::: "memory"); }
            __builtin_amdgcn_s_barrier();       // E: next tile's data resident
        }

        // epilogue: issue stores fire-and-forget (no waitcnt); for half=0
        // they drain under half=1's prologue DMA + K-loop.
        #pragma unroll
        for (int m8 = 0; m8 < 8; ++m8) {
            int m0  = bm0 + wm + m8 * 16 + quad * 4;
            int co0 = m0 >> 1;
            float b0 = bias[co0];
            float b1 = bias[co0 + 1];
            #pragma unroll
            for (int t4 = 0; t4 < 4; ++t4) {
                int t = bt0 + wt + t4 * 16 + l16;
                facc4 v = acc[m8][t4];
                float* p0 = out + ((size_t)(n * CO_ + co0)) * DO_ + 2 * t;
                float* p1 = p0 + DO_;
                *(float2*)p0 = make_float2(v.x + b0, v.y + b0);
                *(float2*)p1 = make_float2(v.z + b1, v.w + b1);
            }
        }
    }
    #undef MM
    #undef MMROW
    #undef LGKM
    #undef STAGE_A
    #undef STAGE_B
}

// ---------------- fallback (round-1 verified kernel) ---------------------
__global__ __launch_bounds__(256) void upconv_fir_f32(
    const float* __restrict__ x, const float* __restrict__ w,
    const float* __restrict__ bias, float* __restrict__ out)
{
    __shared__ float ws[CI_][4];
    const int tid = threadIdx.x;
    const int co  = blockIdx.y;
    const int n   = blockIdx.z;
    {
        const float* wc = w + (size_t)co * CI_ * 3;
        ws[tid][0] = wc[tid * 3 + 0];
        ws[tid][1] = wc[tid * 3 + 1];
        ws[tid][2] = wc[tid * 3 + 2];
        ws[tid][3] = 0.f;
    }
    __syncthreads();
    const int t0 = (blockIdx.x * 256 + tid) * 8;
    const float* xn = x + (size_t)n * CI_ * D_;
    float s[10], g[9];
    #pragma unroll
    for (int k = 0; k < 10; ++k) s[k] = 0.f;
    #pragma unroll
    for (int k = 0; k < 9; ++k) g[k] = 0.f;
    #pragma unroll 2
    for (int ci = 0; ci < CI_; ++ci) {
        const float* xr = xn + ci * D_;
        float4 va = *(const float4*)(xr + t0);
        float4 vb = *(const float4*)(xr + t0 + 4);
        float  xm = (t0 > 0)      ? xr[t0 - 1] : 0.f;
        float  xp = (t0 + 8 < D_) ? xr[t0 + 8] : 0.f;
        float4 wv = *(const float4*)(&ws[ci][0]);
        const float w0 = wv.x, w1 = wv.y, w2 = wv.z;
        float xa[10];
        xa[0] = xm; xa[1] = va.x; xa[2] = va.y; xa[3] = va.z; xa[4] = va.w;
        xa[5] = vb.x; xa[6] = vb.y; xa[7] = vb.z; xa[8] = vb.w; xa[9] = xp;
        #pragma unroll
        for (int k = 0; k < 10; ++k) s[k] += w1 * xa[k];
        #pragma unroll
        for (int k = 0; k < 9; ++k)  g[k] += w0 * xa[k] + w2 * xa[k + 1];
    }
    const float b = bias[co];
    float o16[16];
    #pragma unroll
    for (int tt = 0; tt < 8; ++tt) {
        o16[2 * tt]     = 0.25f * (s[tt] + g[tt + 1]) + 0.75f * (g[tt] + s[tt + 1]) + b;
        o16[2 * tt + 1] = 0.25f * (g[tt] + s[tt + 2]) + 0.75f * (s[tt + 1] + g[tt + 1]) + b;
    }
    float* ob = out + ((size_t)n * CO_ + co) * DO_ + 2 * t0;
    *(float4*)(ob + 0)  = make_float4(o16[0],  o16[1],  o16[2],  o16[3]);
    *(float4*)(ob + 4)  = make_float4(o16[4],  o16[5],  o16[6],  o16[7]);
    *(float4*)(ob + 8)  = make_float4(o16[8],  o16[9],  o16[10], o16[11]);
    *(float4*)(ob + 12) = make_float4(o16[12], o16[13], o16[14], o16[15]);
}

extern "C" void kernel_launch(void* const* d_in, const int* in_sizes, int n_in,
                              void* d_out, int out_size, void* d_ws, size_t ws_size,
                              hipStream_t stream) {
    const float* x  = (const float*)d_in[0];
    const float* w  = (const float*)d_in[1];
    const float* b  = (const float*)d_in[2];
    float* out      = (float*)d_out;

    const size_t need = (size_t)WT_ELEMS * 2 + XT_ELEMS * 2;
    if (ws_size >= need) {
        unsigned short* Wt = (unsigned short*)d_ws;
        unsigned short* xt = Wt + WT_ELEMS;
        prep_all<<<dim3(D_ / 32 + 1, N_), 256, 0, stream>>>(x, w, Wt, xt);
        gemm_upfir8p<<<dim3(D_ / 512, 2, N_), 512, 0, stream>>>(Wt, xt, b, out);
    } else {
        upconv_fir_f32<<<dim3(2, CO_, N_), 256, 0, stream>>>(x, w, b, out);
    }
}

// Round 11
// 235.545 us; speedup vs baseline: 1.0926x; 1.0831x over previous
//
#include <hip/hip_runtime.h>
#include <hip/hip_bf16.h>

#define N_   16
#define CI_  256
#define CO_  256
#define D_   4096
#define DO_  8192
#define KTOT 768            // 3 taps (j outer) x 256 ci
#define XTROWS 4098         // 4096 t + 1 zero pad row each side
#define WT_ELEMS (512 * KTOT)
#define XT_ELEMS ((size_t)N_ * XTROWS * 256)

typedef short frag8 __attribute__((ext_vector_type(8)));   // 8 bf16 (4 VGPR)
typedef float facc4 __attribute__((ext_vector_type(4)));   // 4 f32 acc

static __device__ __forceinline__ unsigned short f2bf(float f) {
    union { __hip_bfloat16 h; unsigned short u; } cv;
    cv.h = __float2bfloat16(f);
    return cv.u;
}

static __device__ __forceinline__ unsigned int pack2(float lo, float hi) {
    return (unsigned int)f2bf(lo) | ((unsigned int)f2bf(hi) << 16);
}

static __device__ __forceinline__ void async16(unsigned short* lds, const unsigned short* g) {
    __builtin_amdgcn_global_load_lds(
        (const __attribute__((address_space(1))) unsigned int*)g,
        (__attribute__((address_space(3))) unsigned int*)lds, 16, 0, 0);
}

// opaque LDS read: no "memory" clobber -> compiler has no alias edge to the
// in-flight global_load_lds writes, so it cannot insert vmcnt(0) drains.
#define DSR_(dst, addr, litstr) \
    asm volatile("ds_read_b128 %0, %1 offset:" litstr : "=&v"(dst) : "v"(addr))

// ---------------- merged prep: weights + x transpose in ONE launch -------
__global__ __launch_bounds__(256) void prep_all(const float* __restrict__ x,
                                                const float* __restrict__ w,
                                                unsigned short* __restrict__ Wt,
                                                unsigned short* __restrict__ xt) {
    const int tid = threadIdx.x;

    if (blockIdx.x == 128) {
        // ---- prep_wt body: co range [y*16, y*16+16) ----
        const int ci = tid;
        #pragma unroll 2
        for (int i = 0; i < 16; ++i) {
            const int co = blockIdx.y * 16 + i;
            const float* wp = w + ((size_t)co * CI_ + ci) * 3;
            const float w0 = wp[0], w1 = wp[1], w2 = wp[2];
            const float e0 = 0.25f * w1 + 0.75f * w0;
            const float e1 = 0.75f * w2 + 0.75f * w1 + 0.25f * w0;
            const float e2 = 0.25f * w2;
            const float o0 = 0.25f * w0;
            const float o1 = 0.25f * w2 + 0.75f * w1 + 0.75f * w0;
            const float o2 = 0.75f * w2 + 0.25f * w1;
            unsigned short* pe = Wt + (size_t)(co * 2 + 0) * KTOT;
            unsigned short* po = Wt + (size_t)(co * 2 + 1) * KTOT;
            pe[0 * 256 + ci] = f2bf(e0); pe[1 * 256 + ci] = f2bf(e1); pe[2 * 256 + ci] = f2bf(e2);
            po[0 * 256 + ci] = f2bf(o0); po[1 * 256 + ci] = f2bf(o1); po[2 * 256 + ci] = f2bf(o2);
        }
        return;
    }

    // ---- prep_xt2 body (verified r0-r10) ----
    __shared__ unsigned int Lp[32][133];   // [t][ci_pair], pitch 133
    const int t0  = blockIdx.x * 32;
    const int n   = blockIdx.y;
    const float* xn = x + (size_t)n * CI_ * D_;
    unsigned short* slab = xt + (size_t)n * XTROWS * 256;

    if (t0 == 0 && tid < 128)       ((unsigned int*)slab)[tid] = 0u;
    if (t0 == D_ - 32 && tid < 128) ((unsigned int*)(slab + (size_t)(XTROWS - 1) * 256))[tid] = 0u;

    const int cp_l  = tid >> 3;
    const int t_off = (tid & 7) * 4;

    #pragma unroll
    for (int p = 0; p < 4; ++p) {
        const int ci0 = p * 64 + cp_l * 2;
        float4 a = *(const float4*)(xn + (size_t)ci0 * D_ + t0 + t_off);
        float4 b = *(const float4*)(xn + (size_t)(ci0 + 1) * D_ + t0 + t_off);
        const int cp = p * 32 + cp_l;
        Lp[t_off + 0][cp] = pack2(a.x, b.x);
        Lp[t_off + 1][cp] = pack2(a.y, b.y);
        Lp[t_off + 2][cp] = pack2(a.z, b.z);
        Lp[t_off + 3][cp] = pack2(a.w, b.w);
    }
    __syncthreads();

    #pragma unroll
    for (int it = 0; it < 4; ++it) {
        const int row = it * 8 + (tid >> 5);
        const int c4  = (tid & 31) * 4;
        uint4 v;
        v.x = Lp[row][c4 + 0];
        v.y = Lp[row][c4 + 1];
        v.z = Lp[row][c4 + 2];
        v.w = Lp[row][c4 + 3];
        *(uint4*)(slab + (size_t)(1 + t0 + row) * 256 + c4 * 2) = v;
    }
}

// ---------------- main: 256m x 256t bf16 MFMA GEMM, 2-barrier K-loop -----
// (byte-identical to round-8 verified best, total 233.85 us)
// 2 barriers/K-tile + counted per-group lgkmcnt so ds_reads overlap MFMA
// (2 waves/SIMD TLP + ILP).  Per wave per K-tile: issue b0-3,a0-3 (16 reads)
// -> lgkm(6) MMROW(0) -> lgkm(4) MMROW(1) -> issue a4-7 -> lgkm(10) MMROW(2)
// -> lgkm(8) MMROW(3) -> lgkm(0), barrier M (re-staging safe) -> stage
// B(u+1), A(u+2) -> MMROW(4..7) (32 MFMA hide DMA) -> vmcnt(4) gate ->
// barrier E.  FIFO audit: gate outstanding = A(u+1)4+B(u+1)4+A(u+2)4 = 12
// -> vmcnt(4) drains A/B(u+1), keeps A(u+2).  Prologue = A0,B0,A1 = 12 ->
// vmcnt(4) leaves A1.  Tail u>=10 -> vmcnt(0).
// Slot-XOR LDS microlayout: 0 bank conflicts (verified r0-r10).
__global__ __launch_bounds__(512, 2) void gemm_upfir8(
    const unsigned short* __restrict__ Wt, const unsigned short* __restrict__ xt,
    const float* __restrict__ bias, float* __restrict__ out)
{
    __shared__ __align__(16) unsigned short SL[65536];   // 128 KiB

    const int tid  = threadIdx.x;
    const int lane = tid & 63;
    const int wid  = tid >> 6;          // 0..7
    const int quad = lane >> 4;
    const int l16  = lane & 15;

    const int bt0 = blockIdx.x * 256;   // t tile
    const int bm0 = blockIdx.y * 256;   // m tile (m = co*2+phase)
    const int n   = blockIdx.z;

    // ---- staging addressing (all 8 waves stage every half-tile) ----
    const int srow = wid * 16 + (lane >> 2);            // 0..127 row in half
    const int cg   = (lane & 3) ^ ((lane >> 3) & 3);    // slot-XOR
    const unsigned short* sA = Wt + (size_t)(bm0 + srow) * KTOT + cg * 8;
    const unsigned short* sB = xt + (size_t)n * XTROWS * 256
                                  + (size_t)(bt0 + srow) * 256 + cg * 8;

    // lds stage dests are wave-uniform (ushort offsets; bytes = 2x)
    #define STAGE_A(u, mh) do {                                                     \
        async16(SL + (((u)&1)*16384 + (mh)*8192 + 0*4096 + wid*512),                \
                sA + (size_t)(mh)*128*KTOT + (u)*64 + 0);                           \
        async16(SL + (((u)&1)*16384 + (mh)*8192 + 1*4096 + wid*512),                \
                sA + (size_t)(mh)*128*KTOT + (u)*64 + 32); } while (0)
    #define STAGE_B(u, th) do {                                                     \
        async16(SL + (32768 + ((u)&1)*16384 + (th)*8192 + 0*4096 + wid*512),        \
                sB + (size_t)(th)*128*256 + (u)*64 + 0);                            \
        async16(SL + (32768 + ((u)&1)*16384 + (th)*8192 + 1*4096 + wid*512),        \
                sB + (size_t)(th)*128*256 + (u)*64 + 32); } while (0)

    // ---- fragment read bases (byte addresses) ----
    const int swz = quad ^ ((l16 >> 1) & 3);
    const int mh  = wid & 1;              // wave m-half
    const int wm  = mh * 128;
    const int wt  = ((wid >> 1) & 3) * 64;
    const unsigned base = (unsigned)(size_t)&SL[0];
    const unsigned aB = base + (unsigned)(mh * 16384 + l16 * 64 + swz * 16);
    const unsigned bB = base + 65536u
                      + (unsigned)(((wid >> 2) & 1) * 16384
                                   + (((wid >> 1) & 1) * 64 + l16) * 64 + swz * 16);

    facc4 acc[8][4] = {};

    // ---- prologue: stage half-tiles A0,B0,A1 (12 loads/thread) ----
    STAGE_A(0, 0); STAGE_A(0, 1); STAGE_B(0, 0); STAGE_B(0, 1);
    STAGE_A(1, 0); STAGE_A(1, 1);
    asm volatile("s_waitcnt vmcnt(4)" ::: "memory");   // K-tile 0 landed, A1 flying
    __builtin_amdgcn_s_barrier();

    #define MM(m, t)                                                                 \
        acc[m][t] = __builtin_amdgcn_mfma_f32_16x16x32_bf16(a[m][0], b[t][0], acc[m][t], 0, 0, 0); \
        acc[m][t] = __builtin_amdgcn_mfma_f32_16x16x32_bf16(a[m][1], b[t][1], acc[m][t], 0, 0, 0);
    #define MMROW(m) MM(m,0) MM(m,1) MM(m,2) MM(m,3)

    #define LGKM(lit) \
        asm volatile("s_waitcnt lgkmcnt(" lit ")" ::: "memory"); \
        __builtin_amdgcn_sched_barrier(0);

    #pragma unroll 2
    for (int u = 0; u < 12; ++u) {
        const unsigned au = aB + (unsigned)((u & 1) << 15);
        const unsigned bu = bB + (unsigned)((u & 1) << 15);
        frag8 a[8][2], b[4][2];

        // issue all B frags + A rows 0-3 (16 ds_reads)
        DSR_(b[0][0], bu, "0");    DSR_(b[0][1], bu, "8192");
        DSR_(b[1][0], bu, "1024"); DSR_(b[1][1], bu, "9216");
        DSR_(b[2][0], bu, "2048"); DSR_(b[2][1], bu, "10240");
        DSR_(b[3][0], bu, "3072"); DSR_(b[3][1], bu, "11264");
        DSR_(a[0][0], au, "0");    DSR_(a[0][1], au, "8192");
        DSR_(a[1][0], au, "1024"); DSR_(a[1][1], au, "9216");
        DSR_(a[2][0], au, "2048"); DSR_(a[2][1], au, "10240");
        DSR_(a[3][0], au, "3072"); DSR_(a[3][1], au, "11264");

        LGKM("6")                           // b0-3 + a0 done
        __builtin_amdgcn_s_setprio(1);
        MMROW(0)
        __builtin_amdgcn_s_setprio(0);
        LGKM("4")                           // a1 done
        __builtin_amdgcn_s_setprio(1);
        MMROW(1)
        __builtin_amdgcn_s_setprio(0);

        // issue A rows 4-7 (8 ds_reads) under the remaining MFMA groups
        DSR_(a[4][0], au, "4096"); DSR_(a[4][1], au, "12288");
        DSR_(a[5][0], au, "5120"); DSR_(a[5][1], au, "13312");
        DSR_(a[6][0], au, "6144"); DSR_(a[6][1], au, "14336");
        DSR_(a[7][0], au, "7168"); DSR_(a[7][1], au, "15360");

        LGKM("10")                          // a2 done
        __builtin_amdgcn_s_setprio(1);
        MMROW(2)
        __builtin_amdgcn_s_setprio(0);
        LGKM("8")                           // a3 done
        __builtin_amdgcn_s_setprio(1);
        MMROW(3)
        __builtin_amdgcn_s_setprio(0);

        LGKM("0")                           // all 24 reads of this tile done
        __builtin_amdgcn_s_barrier();       // M: re-staging is now safe

        if (u < 11) { STAGE_B(u + 1, 0); STAGE_B(u + 1, 1); }
        if (u < 10) { STAGE_A(u + 2, 0); STAGE_A(u + 2, 1); }

        __builtin_amdgcn_s_setprio(1);
        MMROW(4) MMROW(5) MMROW(6) MMROW(7) // 32 MFMA hide the staging DMA
        __builtin_amdgcn_s_setprio(0);

        if (u < 10) { asm volatile("s_waitcnt vmcnt(4)" ::: "memory"); }
        else        { asm volatile("s_waitcnt vmcnt(0)" ::: "memory"); }
        __builtin_amdgcn_s_barrier();       // E: next tile's data resident
    }
    #undef MM
    #undef MMROW
    #undef LGKM
    #undef STAGE_A
    #undef STAGE_B

    // epilogue: D row = quad*4+reg (= m), col = l16 (= t); regs span 2 co x 2 phase
    #pragma unroll
    for (int m8 = 0; m8 < 8; ++m8) {
        int m0  = bm0 + wm + m8 * 16 + quad * 4;
        int co0 = m0 >> 1;
        float b0 = bias[co0];
        float b1 = bias[co0 + 1];
        #pragma unroll
        for (int t4 = 0; t4 < 4; ++t4) {
            int t = bt0 + wt + t4 * 16 + l16;
            facc4 v = acc[m8][t4];
            float* p0 = out + ((size_t)(n * CO_ + co0)) * DO_ + 2 * t;
            float* p1 = p0 + DO_;
            *(float2*)p0 = make_float2(v.x + b0, v.y + b0);
            *(float2*)p1 = make_float2(v.z + b1, v.w + b1);
        }
    }
}

// ---------------- fallback (round-1 verified kernel) ---------------------
__global__ __launch_bounds__(256) void upconv_fir_f32(
    const float* __restrict__ x, const float* __restrict__ w,
    const float* __restrict__ bias, float* __restrict__ out)
{
    __shared__ float ws[CI_][4];
    const int tid = threadIdx.x;
    const int co  = blockIdx.y;
    const int n   = blockIdx.z;
    {
        const float* wc = w + (size_t)co * CI_ * 3;
        ws[tid][0] = wc[tid * 3 + 0];
        ws[tid][1] = wc[tid * 3 + 1];
        ws[tid][2] = wc[tid * 3 + 2];
        ws[tid][3] = 0.f;
    }
    __syncthreads();
    const int t0 = (blockIdx.x * 256 + tid) * 8;
    const float* xn = x + (size_t)n * CI_ * D_;
    float s[10], g[9];
    #pragma unroll
    for (int k = 0; k < 10; ++k) s[k] = 0.f;
    #pragma unroll
    for (int k = 0; k < 9; ++k) g[k] = 0.f;
    #pragma unroll 2
    for (int ci = 0; ci < CI_; ++ci) {
        const float* xr = xn + ci * D_;
        float4 va = *(const float4*)(xr + t0);
        float4 vb = *(const float4*)(xr + t0 + 4);
        float  xm = (t0 > 0)      ? xr[t0 - 1] : 0.f;
        float  xp = (t0 + 8 < D_) ? xr[t0 + 8] : 0.f;
        float4 wv = *(const float4*)(&ws[ci][0]);
        const float w0 = wv.x, w1 = wv.y, w2 = wv.z;
        float xa[10];
        xa[0] = xm; xa[1] = va.x; xa[2] = va.y; xa[3] = va.z; xa[4] = va.w;
        xa[5] = vb.x; xa[6] = vb.y; xa[7] = vb.z; xa[8] = vb.w; xa[9] = xp;
        #pragma unroll
        for (int k = 0; k < 10; ++k) s[k] += w1 * xa[k];
        #pragma unroll
        for (int k = 0; k < 9; ++k)  g[k] += w0 * xa[k] + w2 * xa[k + 1];
    }
    const float b = bias[co];
    float o16[16];
    #pragma unroll
    for (int tt = 0; tt < 8; ++tt) {
        o16[2 * tt]     = 0.25f * (s[tt] + g[tt + 1]) + 0.75f * (g[tt] + s[tt + 1]) + b;
        o16[2 * tt + 1] = 0.25f * (g[tt] + s[tt + 2]) + 0.75f * (s[tt + 1] + g[tt + 1]) + b;
    }
    float* ob = out + ((size_t)n * CO_ + co) * DO_ + 2 * t0;
    *(float4*)(ob + 0)  = make_float4(o16[0],  o16[1],  o16[2],  o16[3]);
    *(float4*)(ob + 4)  = make_float4(o16[4],  o16[5],  o16[6],  o16[7]);
    *(float4*)(ob + 8)  = make_float4(o16[8],  o16[9],  o16[10], o16[11]);
    *(float4*)(ob + 12) = make_float4(o16[12], o16[13], o16[14], o16[15]);
}

extern "C" void kernel_launch(void* const* d_in, const int* in_sizes, int n_in,
                              void* d_out, int out_size, void* d_ws, size_t ws_size,
                              hipStream_t stream) {
    const float* x  = (const float*)d_in[0];
    const float* w  = (const float*)d_in[1];
    const float* b  = (const float*)d_in[2];
    float* out      = (float*)d_out;

    const size_t need = (size_t)WT_ELEMS * 2 + XT_ELEMS * 2;
    if (ws_size >= need) {
        unsigned short* Wt = (unsigned short*)d_ws;
        unsigned short* xt = Wt + WT_ELEMS;
        prep_all<<<dim3(D_ / 32 + 1, N_), 256, 0, stream>>>(x, w, Wt, xt);
        gemm_upfir8<<<dim3(D_ / 256, 2, N_), 512, 0, stream>>>(Wt, xt, b, out);
    } else {
        upconv_fir_f32<<<dim3(2, CO_, N_), 256, 0, stream>>>(x, w, b, out);
    }
}